// Round 1
// baseline (269.942 us; speedup 1.0000x reference)
//
#include <hip/hip_runtime.h>

#define B 4
#define N 2048
#define V 12
#define C 50
#define HH 128
#define WW 128
#define P (HH*WW)   // 16384

// ---------------------------------------------------------------------------
// Kernel 1: per-pixel argmax over C + masked scatter-max into winner[b,v,n].
// 4 pixels per thread via float4/int4; each c-iteration is a coalesced pass.
// ---------------------------------------------------------------------------
__global__ __launch_bounds__(256) void k1_argmax_scatter(
    const float4* __restrict__ predv,    // (B*V, C, P/4) as float4
    const int4*  __restrict__ p2pv,      // (B*V, P/4) as int4
    const int*   __restrict__ parts_nb,  // (B,)
    int*         __restrict__ winner) {  // (B*V, N), pre-init to -1
  const int PQ = P / 4;
  int t = blockIdx.x * 256 + threadIdx.x;
  if (t >= B * V * PQ) return;
  int q  = t % PQ;
  int bv = t / PQ;
  int b  = bv / V;

  size_t base = (size_t)bv * C * PQ + q;
  float4 x = predv[base];
  float b0 = x.x, b1 = x.y, b2 = x.z, b3 = x.w;
  int   a0 = 0,  a1 = 0,  a2 = 0,  a3 = 0;
  for (int c = 1; c < C; ++c) {
    float4 y = predv[base + (size_t)c * PQ];
    if (y.x > b0) { b0 = y.x; a0 = c; }
    if (y.y > b1) { b1 = y.y; a1 = c; }
    if (y.z > b2) { b2 = y.z; a2 = c; }
    if (y.w > b3) { b3 = y.w; a3 = c; }
  }

  int4 pt = p2pv[(size_t)bv * PQ + q];
  int pn = parts_nb[b];
  int p0 = q * 4;
  int* wbase = winner + bv * N;
  // kkey = pred_max*P + pixel; only scatter when mask_pix (else key=-1, no-op)
  if (pt.x != -1 && a0 >= 1 && a0 <= pn) atomicMax(wbase + pt.x, a0 * P + p0);
  if (pt.y != -1 && a1 >= 1 && a1 <= pn) atomicMax(wbase + pt.y, a1 * P + p0 + 1);
  if (pt.z != -1 && a2 >= 1 && a2 <= pn) atomicMax(wbase + pt.z, a2 * P + p0 + 2);
  if (pt.w != -1 && a3 >= 1 && a3 <= pn) atomicMax(wbase + pt.w, a3 * P + p0 + 3);
}

// ---------------------------------------------------------------------------
// Kernel 2: one wave (64 lanes) per (b,n). Loop v: broadcast winner; lanes
// 0..49 gather the 50 logits at win_pix; wave-reduce softmax; accumulate
// vw * softmax; count valid views for denom; write out[b, c, n].
// ---------------------------------------------------------------------------
__global__ __launch_bounds__(256) void k2_gather(
    const float* __restrict__ pred,     // (B*V, C, P)
    const int*   __restrict__ winner,   // (B*V, N)
    const float* __restrict__ vw,       // (B*V,)
    float*       __restrict__ out) {    // (B, C, N)
  int wid  = blockIdx.x * (256 / 64) + (threadIdx.x >> 6);
  int lane = threadIdx.x & 63;
  if (wid >= B * N) return;
  int b = wid / N;
  int n = wid - b * N;

  float acc = 0.f;
  int cnt = 0;
  for (int v = 0; v < V; ++v) {
    int wv = winner[(b * V + v) * N + n];   // same addr across wave -> broadcast
    if (wv < 0) continue;                   // wave-uniform branch
    cnt++;
    int wp = wv & (P - 1);                  // winner % P
    float logit = -3.0e38f;
    if (lane < C)
      logit = pred[(((size_t)(b * V + v)) * C + lane) * P + wp];
    // wave-wide max
    float m = logit;
    #pragma unroll
    for (int off = 32; off > 0; off >>= 1) m = fmaxf(m, __shfl_xor(m, off));
    float e = (lane < C) ? expf(logit - m) : 0.f;
    // wave-wide sum
    float s = e;
    #pragma unroll
    for (int off = 32; off > 0; off >>= 1) s += __shfl_xor(s, off);
    acc += e * (vw[b * V + v] / s);
  }
  float denom = (float)(cnt > 0 ? cnt : 1);
  if (lane < C)
    out[((size_t)b * C + lane) * N + n] = acc / denom;
}

extern "C" void kernel_launch(void* const* d_in, const int* in_sizes, int n_in,
                              void* d_out, int out_size, void* d_ws, size_t ws_size,
                              hipStream_t stream) {
  // inputs: 0=points (unused), 1=predictions_2d f32, 2=rendered_pix_to_point i32,
  //         3=views_weights f32, 4=parts_nb i32
  const float* pred  = (const float*)d_in[1];
  const int*   p2p   = (const int*)d_in[2];
  const float* vw    = (const float*)d_in[3];
  const int*   parts = (const int*)d_in[4];
  float* out = (float*)d_out;
  int* winner = (int*)d_ws;                      // B*V*N ints = 384 KiB

  hipMemsetAsync(winner, 0xFF, (size_t)B * V * N * sizeof(int), stream); // -1 fill

  int nthreads1 = B * V * (P / 4);               // 196608
  k1_argmax_scatter<<<(nthreads1 + 255) / 256, 256, 0, stream>>>(
      (const float4*)pred, (const int4*)p2p, parts, winner);

  k2_gather<<<(B * N) / 4, 256, 0, stream>>>(pred, winner, vw, out);
}